// Round 5
// baseline (271.108 us; speedup 1.0000x reference)
//
#include <hip/hip_runtime.h>

typedef __bf16 bf16x8 __attribute__((ext_vector_type(8)));
typedef float f32x4 __attribute__((ext_vector_type(4)));

#define HW 9216
#define CCH 256

__device__ __forceinline__ unsigned short f2bf(float f) {
  unsigned u = __float_as_uint(f);
  unsigned r = (u + 0x7FFFu + ((u >> 16) & 1u)) >> 16;
  return (unsigned short)r;
}

// y[0..8) += gk * unpack_bf16x8(v)
__device__ __forceinline__ void fma8(float* y, float gk, uint4 v) {
  const unsigned* u = (const unsigned*)&v;
#pragma unroll
  for (int i = 0; i < 4; ++i) {
    y[2 * i] += gk * __uint_as_float(u[i] << 16);
    y[2 * i + 1] += gk * __uint_as_float(u[i] & 0xFFFF0000u);
  }
}

// ---------- x [n][ci][p] fp32 -> xb [n*9216+p][ci] bf16 (LDS tile transpose) ----------
__global__ __launch_bounds__(256) void xpose(const float* __restrict__ x,
                                             unsigned short* __restrict__ xb) {
  __shared__ float tile[64][65];
  int t = threadIdx.x;
  int p0 = blockIdx.x * 64, ci0 = blockIdx.y * 64, n = blockIdx.z;
  int cl = t & 63, q = t >> 6;
#pragma unroll
  for (int i = 0; i < 16; ++i) {
    int cir = q + i * 4;
    tile[cir][cl] = x[((size_t)(n * 256 + ci0 + cir)) * HW + p0 + cl];
  }
  __syncthreads();
#pragma unroll
  for (int i = 0; i < 16; ++i) {
    int pr = q + i * 4;
    xb[((size_t)(n * HW + p0 + pr)) * 256 + ci0 + cl] = f2bf(tile[cl][pr]);
  }
}

// ---------- weight repack: Wsb[j=b*256+co][k=ci] bf16 ; Wcb[co48][k=j*256+ci] bf16 ----------
__global__ __launch_bounds__(256) void prep_w(const float* __restrict__ Ws,
                                              const float* __restrict__ Wc,
                                              unsigned short* __restrict__ Wsb,
                                              unsigned short* __restrict__ Wcb) {
  int u = blockIdx.x * 256 + threadIdx.x;
  if (u < 393216) {
    int j = u >> 8, k = u & 255;
    int co = j & 255, b = j >> 8;
    Wsb[u] = f2bf(Ws[(size_t)co * 1536 + b * 256 + k]);
  } else {
    int v = u - 393216;
    if (v < 110592) {
      int co = v / 2304, r = v % 2304;
      int j = r >> 8, ci = r & 255;
      Wcb[v] = (co < 45) ? f2bf(Wc[(size_t)co * 2304 + ci * 9 + j]) : (unsigned short)0;
    }
  }
}

// ---------- z[m][zc0..zc0+128) = xb . Wsb^T  (MFMA, 128x128 tile, BK=32) ----------
__global__ __launch_bounds__(256) void gemm_z(const unsigned short* __restrict__ xb,
                                              const unsigned short* __restrict__ Wsb,
                                              unsigned short* __restrict__ z, int jbase) {
  __shared__ unsigned short As[4 * 128 * 8];  // [q][mm][j]
  __shared__ unsigned short Bs[4 * 128 * 8];  // [q][nn][j]
  int t = threadIdx.x;
  int m0 = blockIdx.x * 128;
  int jr0 = jbase + blockIdx.y * 128;  // row in Wsb
  int zc0 = blockIdx.y * 128;          // col in z (768-wide local)
  int wid = t >> 6, lane = t & 63;
  int wm = (wid >> 1) * 64, wn = (wid & 1) * 64;
  int q = lane >> 4, ln = lane & 15;
  f32x4 acc[4][4] = {};

  for (int k0 = 0; k0 < 256; k0 += 32) {
#pragma unroll
    for (int r = 0; r < 2; ++r) {
      int idx = t + r * 256;
      int mm = idx >> 2, kq = idx & 3;
      ((uint4*)As)[kq * 128 + mm] =
          *(const uint4*)(xb + (size_t)(m0 + mm) * 256 + k0 + kq * 8);
      ((uint4*)Bs)[kq * 128 + mm] =
          *(const uint4*)(Wsb + (size_t)(jr0 + mm) * 256 + k0 + kq * 8);
    }
    __syncthreads();
    bf16x8 a[4], b[4];
#pragma unroll
    for (int f = 0; f < 4; ++f) {
      a[f] = ((const bf16x8*)As)[q * 128 + wm + f * 16 + ln];
      b[f] = ((const bf16x8*)Bs)[q * 128 + wn + f * 16 + ln];
    }
#pragma unroll
    for (int fm = 0; fm < 4; ++fm)
#pragma unroll
      for (int fn = 0; fn < 4; ++fn)
        acc[fm][fn] = __builtin_amdgcn_mfma_f32_16x16x32_bf16(a[fm], b[fn], acc[fm][fn], 0, 0, 0);
    __syncthreads();
  }

#pragma unroll
  for (int fm = 0; fm < 4; ++fm) {
    int mrow = m0 + wm + fm * 16 + q * 4;
#pragma unroll
    for (int fn = 0; fn < 4; ++fn) {
      int col = zc0 + wn + fn * 16 + ln;
#pragma unroll
      for (int r = 0; r < 4; ++r)
        z[(size_t)(mrow + r) * 768 + col] = f2bf(acc[fm][fn][r]);
    }
  }
}

// ---------- guidance: g45[m][48] = sum_j shift_j(xb) . Wcb^T  (K=2304, BM=64, BN=48) ----------
__global__ __launch_bounds__(256) void gemm_g(const unsigned short* __restrict__ xb,
                                              const unsigned short* __restrict__ Wcb,
                                              float* __restrict__ g45) {
  __shared__ unsigned short As[4 * 64 * 8];
  __shared__ unsigned short Bs[4 * 48 * 8];
  int t = threadIdx.x;
  int m0 = blockIdx.x * 64;
  int wid = t >> 6, lane = t & 63;
  int q = lane >> 4, ln = lane & 15;
  int mm = t >> 2, kq = t & 3;
  int m = m0 + mm;
  int nimg = m / HW, p = m % HW;
  int h = p / 96, w = p % 96;
  int mbase = nimg * HW;
  f32x4 acc[3] = {};

  for (int k0 = 0; k0 < 2304; k0 += 32) {
    int j = k0 >> 8;
    int dy = j / 3 - 1, dx = j % 3 - 1;
    int hh = h + dy, ww = w + dx;
    uint4 av = make_uint4(0, 0, 0, 0);
    if ((unsigned)hh < 96u && (unsigned)ww < 96u)
      av = *(const uint4*)(xb + (size_t)(mbase + hh * 96 + ww) * 256 + (k0 & 255) + kq * 8);
    ((uint4*)As)[kq * 64 + mm] = av;
    if (t < 192) {
      int nn = t >> 2, kq2 = t & 3;
      ((uint4*)Bs)[kq2 * 48 + nn] = *(const uint4*)(Wcb + (size_t)nn * 2304 + k0 + kq2 * 8);
    }
    __syncthreads();
    bf16x8 a = ((const bf16x8*)As)[q * 64 + wid * 16 + ln];
#pragma unroll
    for (int fn = 0; fn < 3; ++fn) {
      bf16x8 b = ((const bf16x8*)Bs)[q * 48 + fn * 16 + ln];
      acc[fn] = __builtin_amdgcn_mfma_f32_16x16x32_bf16(a, b, acc[fn], 0, 0, 0);
    }
    __syncthreads();
  }
#pragma unroll
  for (int fn = 0; fn < 3; ++fn) {
    int col = fn * 16 + ln;
    int mrow = m0 + wid * 16 + q * 4;
#pragma unroll
    for (int r = 0; r < 4; ++r)
      g45[(size_t)(mrow + r) * 48 + col] = acc[fn][r];
  }
}

// ---------- grouped softmax over 5 groups of 9 ----------
__global__ __launch_bounds__(256) void softmax45(const float* __restrict__ g45,
                                                 float* __restrict__ gsm) {
  int m = blockIdx.x * 256 + threadIdx.x;
  const float* g = g45 + (size_t)m * 48;
  float* o = gsm + (size_t)m * 48;
  for (int grp = 0; grp < 5; ++grp) {
    float v[9], mx = -1e30f;
#pragma unroll
    for (int k = 0; k < 9; ++k) { v[k] = g[grp * 9 + k]; mx = fmaxf(mx, v[k]); }
    float s = 0.f;
#pragma unroll
    for (int k = 0; k < 9; ++k) { v[k] = __expf(v[k] - mx); s += v[k]; }
    float inv = 1.f / s;
#pragma unroll
    for (int k = 0; k < 9; ++k) o[grp * 9 + k] = v[k] * inv;
  }
}

// ---------- pass 0: identity + d=1 + d=6. ALL 19 loads batched before any FMA. ----------
// Invalid taps load the (always valid) center address with weight forced to 0,
// so every load is unconditional -> maximal loads-in-flight per wave.
__global__ __launch_bounds__(256, 3) void accum0(const unsigned short* __restrict__ z,
                                                 const float* __restrict__ gsm,
                                                 float* __restrict__ yacc) {
  int t = threadIdx.x;
  int row = t >> 5, c32 = t & 31;
  int m = blockIdx.x * 8 + row;
  int p = m % HW;
  int h = p / 96, w = p % 96;
  const unsigned short* zrow = z + (size_t)m * 768 + c32 * 8;
  const float* gr = gsm + (size_t)m * 48;

  uint4 zid = *(const uint4*)zrow;  // identity, slice 0
  uint4 zv[18];
  float gk[18];
#pragma unroll
  for (int bl = 0; bl < 2; ++bl) {
    const int d = bl ? 6 : 1;
    const int slice = bl + 1;
#pragma unroll
    for (int k = 0; k < 9; ++k) {
      const int idx = bl * 9 + k;
      const int DY = (k / 3 - 1) * d, DX = (k % 3 - 1) * d;
      bool valid = ((unsigned)(h + DY) < 96u) & ((unsigned)(w + DX) < 96u);
      const int off = (DY * 96 + DX) * 768 + slice * 256;
      zv[idx] = *(const uint4*)(zrow + (valid ? off : slice * 256));
      gk[idx] = valid ? gr[bl * 9 + k] : 0.f;
    }
  }

  float y[8];
#pragma unroll
  for (int j = 0; j < 8; ++j) y[j] = 0.f;
  fma8(y, 1.f, zid);
#pragma unroll
  for (int idx = 0; idx < 18; ++idx) fma8(y, gk[idx], zv[idx]);

  size_t ybase = (size_t)m * 256 + c32 * 8;
  *(float4*)(yacc + ybase) = make_float4(y[0], y[1], y[2], y[3]);
  *(float4*)(yacc + ybase + 4) = make_float4(y[4], y[5], y[6], y[7]);
}

// ---------- pass 1: d=12,24,36 (27 taps) + yacc RMW + BN stats ----------
__global__ __launch_bounds__(256, 3) void accum1(const unsigned short* __restrict__ z,
                                                 const float* __restrict__ gsm,
                                                 float* __restrict__ yacc,
                                                 float* __restrict__ stats) {
  __shared__ float red[8][256];
  int t = threadIdx.x;
  int row = t >> 5, c32 = t & 31;
  int m = blockIdx.x * 8 + row;
  int p = m % HW;
  int h = p / 96, w = p % 96;
  const unsigned short* zrow = z + (size_t)m * 768 + c32 * 8;
  const float* gr = gsm + (size_t)m * 48;
  size_t ybase = (size_t)m * 256 + c32 * 8;

  float4 y0 = *(const float4*)(yacc + ybase);
  float4 y1 = *(const float4*)(yacc + ybase + 4);

  uint4 zv[27];
  float gk[27];
#pragma unroll
  for (int bl = 0; bl < 3; ++bl) {
    const int d = bl == 0 ? 12 : (bl == 1 ? 24 : 36);
    const int slice = bl;
    const int goff = (bl + 2) * 9;  // branches 3,4,5 -> gsm offsets 18,27,36
#pragma unroll
    for (int k = 0; k < 9; ++k) {
      const int idx = bl * 9 + k;
      const int DY = (k / 3 - 1) * d, DX = (k % 3 - 1) * d;
      bool valid = ((unsigned)(h + DY) < 96u) & ((unsigned)(w + DX) < 96u);
      const int off = (DY * 96 + DX) * 768 + slice * 256;
      zv[idx] = *(const uint4*)(zrow + (valid ? off : slice * 256));
      gk[idx] = valid ? gr[goff + k] : 0.f;
    }
  }

  float y[8] = {y0.x, y0.y, y0.z, y0.w, y1.x, y1.y, y1.z, y1.w};
#pragma unroll
  for (int idx = 0; idx < 27; ++idx) fma8(y, gk[idx], zv[idx]);

  *(float4*)(yacc + ybase) = make_float4(y[0], y[1], y[2], y[3]);
  *(float4*)(yacc + ybase + 4) = make_float4(y[4], y[5], y[6], y[7]);

  // BN stats: per-channel sum & sumsq via one reused 8KB LDS buffer
#pragma unroll
  for (int j = 0; j < 8; ++j) red[row][c32 * 8 + j] = y[j];
  __syncthreads();
  float a = 0.f;
#pragma unroll
  for (int r = 0; r < 8; ++r) a += red[r][t];
  atomicAdd(&stats[t], a);
  __syncthreads();
#pragma unroll
  for (int j = 0; j < 8; ++j) red[row][c32 * 8 + j] = y[j] * y[j];
  __syncthreads();
  float b = 0.f;
#pragma unroll
  for (int r = 0; r < 8; ++r) b += red[r][t];
  atomicAdd(&stats[256 + t], b);
}

// ---------- normalize + affine + transpose [m][co] -> [n][co][p] ----------
__global__ __launch_bounds__(256) void bn_apply(const float* __restrict__ yacc,
                                                const float* __restrict__ stats,
                                                const float* __restrict__ gamma,
                                                const float* __restrict__ beta,
                                                float* __restrict__ out) {
  __shared__ float tile[64][65];
  int t = threadIdx.x;
  int p0 = blockIdx.x * 64, co0 = blockIdx.y * 64, n = blockIdx.z;
  int cl = t & 63, q = t >> 6;
#pragma unroll
  for (int i = 0; i < 16; ++i) {
    int pr = q + i * 4;
    tile[pr][cl] = yacc[((size_t)n * HW + p0 + pr) * 256 + co0 + cl];
  }
  __syncthreads();
  const float inv_cnt = 1.f / 18432.f;
#pragma unroll
  for (int i = 0; i < 16; ++i) {
    int cr = q + i * 4;
    int c = co0 + cr;
    float mean = stats[c] * inv_cnt;
    float var = stats[256 + c] * inv_cnt - mean * mean;
    float sc = rsqrtf(var + 1e-5f) * gamma[c];
    float sh = beta[c] - mean * sc;
    out[(size_t)(n * 256 + c) * HW + p0 + cl] = tile[cl][cr] * sc + sh;
  }
}

extern "C" void kernel_launch(void* const* d_in, const int* in_sizes, int n_in,
                              void* d_out, int out_size, void* d_ws, size_t ws_size,
                              hipStream_t stream) {
  const float* x = (const float*)d_in[0];
  const float* Wc = (const float*)d_in[1];
  const float* Ws = (const float*)d_in[2];
  const float* gamma = (const float*)d_in[3];
  const float* beta = (const float*)d_in[4];
  float* out = (float*)d_out;

  unsigned short* xb = (unsigned short*)d_ws;      // 4718592 bf16
  unsigned short* Wsb = xb + 4718592;              // 393216 bf16
  unsigned short* Wcb = Wsb + 393216;              // 110592 bf16
  unsigned short* z = Wcb + 110592;                // 14155776 bf16 (18432 x 768)
  float* g45 = (float*)(z + 14155776);             // 884736 f32
  float* gsm = g45 + 884736;                       // 884736 f32
  float* yacc = gsm + 884736;                      // 4718592 f32
  float* stats = yacc + 4718592;                   // 512 f32   (total ~64.7 MB)

  hipMemsetAsync(stats, 0, 512 * sizeof(float), stream);
  xpose<<<dim3(144, 4, 2), 256, 0, stream>>>(x, xb);
  prep_w<<<1968, 256, 0, stream>>>(Ws, Wc, Wsb, Wcb);
  gemm_g<<<288, 256, 0, stream>>>(xb, Wcb, g45);
  softmax45<<<72, 256, 0, stream>>>(g45, gsm);

  gemm_z<<<dim3(144, 6), 256, 0, stream>>>(xb, Wsb, z, 0);
  accum0<<<2304, 256, 0, stream>>>(z, gsm, yacc);
  gemm_z<<<dim3(144, 6), 256, 0, stream>>>(xb, Wsb, z, 768);
  accum1<<<2304, 256, 0, stream>>>(z, gsm, yacc, stats);

  bn_apply<<<dim3(144, 4, 2), 256, 0, stream>>>(yacc, stats, gamma, beta, out);
}

// Round 6
// 237.541 us; speedup vs baseline: 1.1413x; 1.1413x over previous
//
#include <hip/hip_runtime.h>

typedef __bf16 bf16x8 __attribute__((ext_vector_type(8)));
typedef float f32x4 __attribute__((ext_vector_type(4)));

#define HW 9216
#define CCH 256

__device__ __forceinline__ unsigned short f2bf(float f) {
  unsigned u = __float_as_uint(f);
  unsigned r = (u + 0x7FFFu + ((u >> 16) & 1u)) >> 16;
  return (unsigned short)r;
}
__device__ __forceinline__ float bf2f(unsigned short h) {
  return __uint_as_float(((unsigned)h) << 16);
}

// async 16B/lane global->LDS DMA; LDS dst = wave-uniform base + lane*16
__device__ __forceinline__ void async16(const unsigned short* g, unsigned short* l) {
  __builtin_amdgcn_global_load_lds(
      (const __attribute__((address_space(1))) unsigned int*)g,
      (__attribute__((address_space(3))) unsigned int*)l, 16, 0, 0);
}

// y[0..8) += gk * unpack_bf16x8(v)
__device__ __forceinline__ void fma8(float* y, float gk, uint4 v) {
  const unsigned* u = (const unsigned*)&v;
#pragma unroll
  for (int i = 0; i < 4; ++i) {
    y[2 * i] += gk * __uint_as_float(u[i] << 16);
    y[2 * i + 1] += gk * __uint_as_float(u[i] & 0xFFFF0000u);
  }
}

// ---------- x [n][ci][p] fp32 -> xb [n*9216+p][ci] bf16 ----------
__global__ __launch_bounds__(256) void xpose(const float* __restrict__ x,
                                             unsigned short* __restrict__ xb) {
  __shared__ float tile[64][65];
  int t = threadIdx.x;
  int p0 = blockIdx.x * 64, ci0 = blockIdx.y * 64, n = blockIdx.z;
  int cl = t & 63, q = t >> 6;
#pragma unroll
  for (int i = 0; i < 16; ++i) {
    int cir = q + i * 4;
    tile[cir][cl] = x[((size_t)(n * 256 + ci0 + cir)) * HW + p0 + cl];
  }
  __syncthreads();
#pragma unroll
  for (int i = 0; i < 16; ++i) {
    int pr = q + i * 4;
    xb[((size_t)(n * HW + p0 + pr)) * 256 + ci0 + cl] = f2bf(tile[cl][pr]);
  }
}

// ---------- weight repack ----------
__global__ __launch_bounds__(256) void prep_w(const float* __restrict__ Ws,
                                              const float* __restrict__ Wc,
                                              unsigned short* __restrict__ Wsb,
                                              unsigned short* __restrict__ Wcb) {
  int u = blockIdx.x * 256 + threadIdx.x;
  if (u < 393216) {
    int j = u >> 8, k = u & 255;
    int co = j & 255, b = j >> 8;
    Wsb[u] = f2bf(Ws[(size_t)co * 1536 + b * 256 + k]);
  } else {
    int v = u - 393216;
    if (v < 110592) {
      int co = v / 2304, r = v % 2304;
      int j = r >> 8, ci = r & 255;
      Wcb[v] = (co < 45) ? f2bf(Wc[(size_t)co * 2304 + ci * 9 + j]) : (unsigned short)0;
    }
  }
}

// ---------- gemm_z: out slice-major z[slice][m][256] ----------
__global__ __launch_bounds__(256) void gemm_z(const unsigned short* __restrict__ xb,
                                              const unsigned short* __restrict__ Wsb,
                                              unsigned short* __restrict__ z, int jbase) {
  __shared__ unsigned short As[4 * 128 * 8];
  __shared__ unsigned short Bs[4 * 128 * 8];
  int t = threadIdx.x;
  int m0 = blockIdx.x * 128;
  int jr0 = jbase + blockIdx.y * 128;
  int zc0 = blockIdx.y * 128;
  int wid = t >> 6, lane = t & 63;
  int wm = (wid >> 1) * 64, wn = (wid & 1) * 64;
  int q = lane >> 4, ln = lane & 15;
  f32x4 acc[4][4] = {};

  for (int k0 = 0; k0 < 256; k0 += 32) {
#pragma unroll
    for (int r = 0; r < 2; ++r) {
      int idx = t + r * 256;
      int mm = idx >> 2, kq = idx & 3;
      ((uint4*)As)[kq * 128 + mm] =
          *(const uint4*)(xb + (size_t)(m0 + mm) * 256 + k0 + kq * 8);
      ((uint4*)Bs)[kq * 128 + mm] =
          *(const uint4*)(Wsb + (size_t)(jr0 + mm) * 256 + k0 + kq * 8);
    }
    __syncthreads();
    bf16x8 a[4], b[4];
#pragma unroll
    for (int f = 0; f < 4; ++f) {
      a[f] = ((const bf16x8*)As)[q * 128 + wm + f * 16 + ln];
      b[f] = ((const bf16x8*)Bs)[q * 128 + wn + f * 16 + ln];
    }
#pragma unroll
    for (int fm = 0; fm < 4; ++fm)
#pragma unroll
      for (int fn = 0; fn < 4; ++fn)
        acc[fm][fn] = __builtin_amdgcn_mfma_f32_16x16x32_bf16(a[fm], b[fn], acc[fm][fn], 0, 0, 0);
    __syncthreads();
  }

#pragma unroll
  for (int fm = 0; fm < 4; ++fm) {
    int mrow = m0 + wm + fm * 16 + q * 4;
#pragma unroll
    for (int fn = 0; fn < 4; ++fn) {
      int col = zc0 + wn + fn * 16 + ln;
      int sl = col >> 8, cc = col & 255;
#pragma unroll
      for (int r = 0; r < 4; ++r)
        z[((size_t)sl * 18432 + mrow + r) * 256 + cc] = f2bf(acc[fm][fn][r]);
    }
  }
}

// ---------- guidance GEMM (unchanged) ----------
__global__ __launch_bounds__(256) void gemm_g(const unsigned short* __restrict__ xb,
                                              const unsigned short* __restrict__ Wcb,
                                              float* __restrict__ g45) {
  __shared__ unsigned short As[4 * 64 * 8];
  __shared__ unsigned short Bs[4 * 48 * 8];
  int t = threadIdx.x;
  int m0 = blockIdx.x * 64;
  int wid = t >> 6, lane = t & 63;
  int q = lane >> 4, ln = lane & 15;
  int mm = t >> 2, kq = t & 3;
  int m = m0 + mm;
  int nimg = m / HW, p = m % HW;
  int h = p / 96, w = p % 96;
  int mbase = nimg * HW;
  f32x4 acc[3] = {};

  for (int k0 = 0; k0 < 2304; k0 += 32) {
    int j = k0 >> 8;
    int dy = j / 3 - 1, dx = j % 3 - 1;
    int hh = h + dy, ww = w + dx;
    uint4 av = make_uint4(0, 0, 0, 0);
    if ((unsigned)hh < 96u && (unsigned)ww < 96u)
      av = *(const uint4*)(xb + (size_t)(mbase + hh * 96 + ww) * 256 + (k0 & 255) + kq * 8);
    ((uint4*)As)[kq * 64 + mm] = av;
    if (t < 192) {
      int nn = t >> 2, kq2 = t & 3;
      ((uint4*)Bs)[kq2 * 48 + nn] = *(const uint4*)(Wcb + (size_t)nn * 2304 + k0 + kq2 * 8);
    }
    __syncthreads();
    bf16x8 a = ((const bf16x8*)As)[q * 64 + wid * 16 + ln];
#pragma unroll
    for (int fn = 0; fn < 3; ++fn) {
      bf16x8 b = ((const bf16x8*)Bs)[q * 48 + fn * 16 + ln];
      acc[fn] = __builtin_amdgcn_mfma_f32_16x16x32_bf16(a, b, acc[fn], 0, 0, 0);
    }
    __syncthreads();
  }
#pragma unroll
  for (int fn = 0; fn < 3; ++fn) {
    int col = fn * 16 + ln;
    int mrow = m0 + wid * 16 + q * 4;
#pragma unroll
    for (int r = 0; r < 4; ++r)
      g45[(size_t)(mrow + r) * 48 + col] = acc[fn][r];
  }
}

// ---------- softmax -> bf16 col-major gsmb[col][img][p] ----------
__global__ __launch_bounds__(256) void softmax45(const float* __restrict__ g45,
                                                 unsigned short* __restrict__ gsmb) {
  int m = blockIdx.x * 256 + threadIdx.x;
  int img = m / HW, p = m % HW;
  const float* g = g45 + (size_t)m * 48;
  for (int grp = 0; grp < 5; ++grp) {
    float v[9], mx = -1e30f;
#pragma unroll
    for (int k = 0; k < 9; ++k) { v[k] = g[grp * 9 + k]; mx = fmaxf(mx, v[k]); }
    float s = 0.f;
#pragma unroll
    for (int k = 0; k < 9; ++k) { v[k] = __expf(v[k] - mx); s += v[k]; }
    float inv = 1.f / s;
#pragma unroll
    for (int k = 0; k < 9; ++k) {
      int col = grp * 9 + k;
      gsmb[((size_t)(col * 2 + img)) * HW + p] = f2bf(v[k] * inv);
    }
  }
}

// ---------- accum: one image row (96px) x 32ch per block, async-LDS staged ----------
// PASS0: identity + d=1 + d=6 (7 z-rows, 18 weight cols). PASS1: d=12,24,36 (9 rows,
// 27 cols) + BN stats. 384 threads = 96px x 4 ch-chunks.
__constant__ const int SLa[2][9] = {{0, 1, 1, 1, 2, 2, 2, 0, 0},
                                    {0, 0, 0, 1, 1, 1, 2, 2, 2}};
__constant__ const int DYa[2][9] = {{0, -1, 0, 1, -6, 0, 6, 0, 0},
                                    {-12, 0, 12, -24, 0, 24, -36, 0, 36}};

template <int PASS>
__global__ __launch_bounds__(384, 3) void accum_rows(const unsigned short* __restrict__ z,
                                                     const unsigned short* __restrict__ gsmb,
                                                     float* __restrict__ yacc,
                                                     float* __restrict__ stats) {
  constexpr int NR = PASS ? 9 : 7;
  constexpr int NC = PASS ? 27 : 18;
  __shared__ unsigned short rows[NR * 3072];  // [slot][96px][32ch]
  __shared__ unsigned short gw[NC * 96];      // [colLocal][96px] bf16
  int t = threadIdx.x;
  int h = blockIdx.x, img = blockIdx.y, cg = blockIdx.z;
  int wid = t >> 6, lane = t & 63;

  // ---- stage z rows (async, zero VGPR results) ----
#pragma unroll
  for (int r = 0; r < NR; ++r) {
    int hr = min(max(h + DYa[PASS][r], 0), 95);
    const unsigned short* src =
        z + ((size_t)(SLa[PASS][r] * 18432 + img * HW + hr * 96)) * 256 + cg * 32;
    int pc = wid;  // 6 chunks of 16px <-> 6 waves
    int px = pc * 16 + (lane >> 2);
    async16(src + (size_t)px * 256 + (lane & 3) * 8, &rows[r * 3072 + pc * 512]);
  }
  // ---- stage weight rows ----
  for (int c = wid; c < NC; c += 6) {
    int gc = (PASS ? 18 : 0) + c;
    const unsigned short* src = gsmb + ((size_t)(gc * 2 + img)) * HW + h * 96;
    if (lane < 12) async16(src + lane * 8, &gw[c * 96]);
  }
  __syncthreads();  // drains vmcnt

  // ---- compute ----
  int c8 = t & 3, px = t >> 2;  // px in [0,96)
  bool rv[9];
#pragma unroll
  for (int r = 0; r < NR; ++r) rv[r] = (unsigned)(h + DYa[PASS][r]) < 96u;

  float y[8];
  size_t ybase = ((size_t)img * HW + h * 96 + px) * 256 + cg * 32 + c8 * 8;
  if (PASS) {
    float4 y0 = *(const float4*)(yacc + ybase);
    float4 y1 = *(const float4*)(yacc + ybase + 4);
    y[0] = y0.x; y[1] = y0.y; y[2] = y0.z; y[3] = y0.w;
    y[4] = y1.x; y[5] = y1.y; y[6] = y1.z; y[7] = y1.w;
  } else {
#pragma unroll
    for (int j = 0; j < 8; ++j) y[j] = 0.f;
    fma8(y, 1.f, *(const uint4*)&rows[px * 32 + c8 * 8]);  // identity (slot 0)
  }

  constexpr int NB = PASS ? 3 : 2;
#pragma unroll
  for (int b = 0; b < NB; ++b) {
    const int d = PASS ? (b == 0 ? 12 : (b == 1 ? 24 : 36)) : (b == 0 ? 1 : 6);
    const int slotbase = PASS ? b * 3 : 1 + b * 3;
#pragma unroll
    for (int k = 0; k < 9; ++k) {
      const int slot = slotbase + k / 3;
      const int dx = (k % 3 - 1) * d;
      int wt = px + dx;
      bool valid = rv[slot] && ((unsigned)wt < 96u);
      int widx = valid ? wt : px;
      float gk = valid ? bf2f(gw[(b * 9 + k) * 96 + px]) : 0.f;
      uint4 v = *(const uint4*)&rows[slot * 3072 + widx * 32 + c8 * 8];
      fma8(y, gk, v);
    }
  }

  *(float4*)(yacc + ybase) = make_float4(y[0], y[1], y[2], y[3]);
  *(float4*)(yacc + ybase + 4) = make_float4(y[4], y[5], y[6], y[7]);

  if (PASS) {  // BN stats: shfl over px-lanes, LDS over waves, atomics per block
    float s[8], s2[8];
#pragma unroll
    for (int j = 0; j < 8; ++j) { s[j] = y[j]; s2[j] = y[j] * y[j]; }
#pragma unroll
    for (int off = 4; off <= 32; off <<= 1) {
#pragma unroll
      for (int j = 0; j < 8; ++j) {
        s[j] += __shfl_xor(s[j], off);
        s2[j] += __shfl_xor(s2[j], off);
      }
    }
    __syncthreads();  // all gw reads done before aliasing
    float* red2 = (float*)gw;  // [6 waves][4 c8][16]
    if (lane < 4) {
#pragma unroll
      for (int j = 0; j < 8; ++j) {
        red2[(wid * 4 + lane) * 16 + j] = s[j];
        red2[(wid * 4 + lane) * 16 + 8 + j] = s2[j];
      }
    }
    __syncthreads();
    if (t < 64) {
      int chl = t >> 1, st = t & 1;
      float a = 0.f;
#pragma unroll
      for (int w2 = 0; w2 < 6; ++w2)
        a += red2[(w2 * 4 + (chl >> 3)) * 16 + st * 8 + (chl & 7)];
      atomicAdd(&stats[st * 256 + cg * 32 + chl], a);
    }
  }
}

// ---------- normalize + affine + transpose ----------
__global__ __launch_bounds__(256) void bn_apply(const float* __restrict__ yacc,
                                                const float* __restrict__ stats,
                                                const float* __restrict__ gamma,
                                                const float* __restrict__ beta,
                                                float* __restrict__ out) {
  __shared__ float tile[64][65];
  int t = threadIdx.x;
  int p0 = blockIdx.x * 64, co0 = blockIdx.y * 64, n = blockIdx.z;
  int cl = t & 63, q = t >> 6;
#pragma unroll
  for (int i = 0; i < 16; ++i) {
    int pr = q + i * 4;
    tile[pr][cl] = yacc[((size_t)n * HW + p0 + pr) * 256 + co0 + cl];
  }
  __syncthreads();
  const float inv_cnt = 1.f / 18432.f;
#pragma unroll
  for (int i = 0; i < 16; ++i) {
    int cr = q + i * 4;
    int c = co0 + cr;
    float mean = stats[c] * inv_cnt;
    float var = stats[256 + c] * inv_cnt - mean * mean;
    float sc = rsqrtf(var + 1e-5f) * gamma[c];
    float sh = beta[c] - mean * sc;
    out[(size_t)(n * 256 + c) * HW + p0 + cl] = tile[cl][cr] * sc + sh;
  }
}

extern "C" void kernel_launch(void* const* d_in, const int* in_sizes, int n_in,
                              void* d_out, int out_size, void* d_ws, size_t ws_size,
                              hipStream_t stream) {
  const float* x = (const float*)d_in[0];
  const float* Wc = (const float*)d_in[1];
  const float* Ws = (const float*)d_in[2];
  const float* gamma = (const float*)d_in[3];
  const float* beta = (const float*)d_in[4];
  float* out = (float*)d_out;

  unsigned short* xb = (unsigned short*)d_ws;   // 4718592 us
  unsigned short* Wsb = xb + 4718592;           // 393216 us
  unsigned short* Wcb = Wsb + 393216;           // 110592 us
  unsigned short* z = Wcb + 110592;             // 14155776 us  [3 slices][18432][256]
  unsigned short* gsmb = z + 14155776;          // 829440 us    [45][2][9216]
  float* g45 = (float*)(gsmb + 829440);         // 884736 f32
  float* yacc = g45 + 884736;                   // 4718592 f32
  float* stats = yacc + 4718592;                // 512 f32   (total ~61.1 MB)

  hipMemsetAsync(stats, 0, 512 * sizeof(float), stream);
  xpose<<<dim3(144, 4, 2), 256, 0, stream>>>(x, xb);
  prep_w<<<1968, 256, 0, stream>>>(Ws, Wc, Wsb, Wcb);
  gemm_g<<<288, 256, 0, stream>>>(xb, Wcb, g45);
  softmax45<<<72, 256, 0, stream>>>(g45, gsmb);

  gemm_z<<<dim3(144, 6), 256, 0, stream>>>(xb, Wsb, z, 0);
  accum_rows<0><<<dim3(96, 2, 8), 384, 0, stream>>>(z, gsmb, yacc, stats);
  gemm_z<<<dim3(144, 6), 256, 0, stream>>>(xb, Wsb, z, 768);
  accum_rows<1><<<dim3(96, 2, 8), 384, 0, stream>>>(z, gsmb, yacc, stats);

  bn_apply<<<dim3(144, 4, 2), 256, 0, stream>>>(yacc, stats, gamma, beta, out);
}